// Round 1
// baseline (1212.117 us; speedup 1.0000x reference)
//
#include <hip/hip_runtime.h>
#include <math.h>

#define B_ 8
#define N_ 1024
#define C_ 768
#define H_ 8
#define D_ 96
#define SCALE_F 0.1020620726159657f  /* 96^-0.5 */

// ---------------------------------------------------------------------------
// Kernel 1: conv3x3 (SAME) on 8192 images of 3x16x16, three weight sets (q,k,v)
// Output layout: (B, H, N, D) with c = oc*256 + y*16 + x, h = c/96, d = c%96
// ---------------------------------------------------------------------------
__global__ __launch_bounds__(256) void conv_qkv(
    const float* __restrict__ x,
    const float* __restrict__ qw, const float* __restrict__ qb,
    const float* __restrict__ kw, const float* __restrict__ kb,
    const float* __restrict__ vw, const float* __restrict__ vb,
    float* __restrict__ q, float* __restrict__ k, float* __restrict__ v)
{
    __shared__ float simg[768];
    __shared__ float sw[243];
    __shared__ float sb[9];
    const int img = blockIdx.x;
    const int b = img >> 10, n = img & 1023;
    const int tid = threadIdx.x;

    for (int i = tid; i < 768; i += 256) simg[i] = x[(size_t)img * 768 + i];
    if (tid < 243) {
        int g = tid / 81, i = tid % 81;
        const float* w = (g == 0) ? qw : (g == 1) ? kw : vw;
        sw[tid] = w[i];
    }
    if (tid < 9) {
        int g = tid / 3, i = tid % 3;
        const float* bb = (g == 0) ? qb : (g == 1) ? kb : vb;
        sb[tid] = bb[i];
    }
    __syncthreads();

    for (int e = tid; e < 2304; e += 256) {
        int g = e / 768, c = e % 768;
        int oc = c >> 8, rem = c & 255, y = rem >> 4, xx = rem & 15;
        float acc = sb[g * 3 + oc];
        const float* wg = &sw[g * 81 + oc * 27];
        #pragma unroll
        for (int ic = 0; ic < 3; ++ic) {
            #pragma unroll
            for (int ky = 0; ky < 3; ++ky) {
                int yy = y + ky - 1;
                if (yy < 0 || yy > 15) continue;
                #pragma unroll
                for (int kx = 0; kx < 3; ++kx) {
                    int xp = xx + kx - 1;
                    if (xp < 0 || xp > 15) continue;
                    acc += wg[ic * 9 + ky * 3 + kx] * simg[ic * 256 + yy * 16 + xp];
                }
            }
        }
        int h = c / 96, d = c % 96;
        float* dst = (g == 0) ? q : (g == 1) ? k : v;
        dst[((size_t)(b * 8 + h) * 1024 + n) * 96 + d] = acc;
    }
}

// ---------------------------------------------------------------------------
// Kernel 2: logits[b,h,n,m] = SCALE * dot(q[b,h,n,:], k[b,h,m,:])
// 128x128 tile, 8x8 per thread, K staged transposed in LDS.
// ---------------------------------------------------------------------------
__global__ __launch_bounds__(256) void qk_gemm(
    const float* __restrict__ q, const float* __restrict__ k,
    float* __restrict__ logits)
{
    const int bh = blockIdx.z;
    const float* qp = q + (size_t)bh * N_ * D_;
    const float* kp = k + (size_t)bh * N_ * D_;
    float* lp = logits + (size_t)bh * N_ * N_;
    const int n0 = blockIdx.y * 128, m0 = blockIdx.x * 128;

    __shared__ __align__(16) float As[32][132];  // [kk][n]
    __shared__ __align__(16) float Bs[32][132];  // [kk][m]

    float acc[8][8];
    #pragma unroll
    for (int i = 0; i < 8; ++i)
        #pragma unroll
        for (int j = 0; j < 8; ++j) acc[i][j] = 0.f;

    const int tid = threadIdx.x, tx = tid & 15, ty = tid >> 4;

    for (int kc = 0; kc < 96; kc += 32) {
        #pragma unroll
        for (int it = 0; it < 16; ++it) {
            int e = tid + it * 256;
            int i = e >> 5, kk = e & 31;
            As[kk][i] = qp[(size_t)(n0 + i) * 96 + kc + kk];
            Bs[kk][i] = kp[(size_t)(m0 + i) * 96 + kc + kk];
        }
        __syncthreads();
        #pragma unroll
        for (int kk = 0; kk < 32; ++kk) {
            float4 a0 = *(const float4*)&As[kk][ty * 8];
            float4 a1 = *(const float4*)&As[kk][ty * 8 + 4];
            float4 b0 = *(const float4*)&Bs[kk][tx * 8];
            float4 b1 = *(const float4*)&Bs[kk][tx * 8 + 4];
            float av[8] = {a0.x, a0.y, a0.z, a0.w, a1.x, a1.y, a1.z, a1.w};
            float bv[8] = {b0.x, b0.y, b0.z, b0.w, b1.x, b1.y, b1.z, b1.w};
            #pragma unroll
            for (int i = 0; i < 8; ++i)
                #pragma unroll
                for (int j = 0; j < 8; ++j)
                    acc[i][j] += av[i] * bv[j];
        }
        __syncthreads();
    }

    #pragma unroll
    for (int i = 0; i < 8; ++i) {
        size_t row = (size_t)(n0 + ty * 8 + i) * 1024 + m0 + tx * 8;
        float4 s0 = make_float4(acc[i][0] * SCALE_F, acc[i][1] * SCALE_F,
                                acc[i][2] * SCALE_F, acc[i][3] * SCALE_F);
        float4 s1 = make_float4(acc[i][4] * SCALE_F, acc[i][5] * SCALE_F,
                                acc[i][6] * SCALE_F, acc[i][7] * SCALE_F);
        *(float4*)&lp[row] = s0;
        *(float4*)&lp[row + 4] = s1;
    }
}

// ---------------------------------------------------------------------------
// Kernel 3: per (b, n): softmax each of 8 head-rows (length 1024), then
// head-mix (rw) + bias (rb) + BatchNorm (eval) fused; in-place on d_out attn.
// ---------------------------------------------------------------------------
__global__ __launch_bounds__(256) void softmax_mix(
    float* __restrict__ attn,
    const float* __restrict__ rw, const float* __restrict__ rb,
    const float* __restrict__ bn_g, const float* __restrict__ bn_b,
    const float* __restrict__ bn_m, const float* __restrict__ bn_v)
{
    __shared__ float p[8][1024];
    __shared__ float s_w2[8][8];
    __shared__ float s_bias2[8];

    const int bn_idx = blockIdx.x;
    const int b = bn_idx >> 10, n = bn_idx & 1023;
    const int tid = threadIdx.x;

    if (tid < 64) {
        int o = tid >> 3, h = tid & 7;
        float inv = bn_g[o] * rsqrtf(bn_v[o] + 1e-5f);
        s_w2[o][h] = rw[o * 8 + h] * inv;
        if (h == 0) s_bias2[o] = (rb[o] - bn_m[o]) * inv + bn_b[o];
    }

    #pragma unroll
    for (int h = 0; h < 8; ++h)
        for (int m = tid; m < 1024; m += 256)
            p[h][m] = attn[((size_t)(b * 8 + h) * 1024 + n) * 1024 + m];
    __syncthreads();

    const int wave = tid >> 6, lane = tid & 63;
    #pragma unroll
    for (int r = 0; r < 2; ++r) {
        int h = wave * 2 + r;
        float mx = -INFINITY;
        for (int m = lane; m < 1024; m += 64) mx = fmaxf(mx, p[h][m]);
        #pragma unroll
        for (int off = 32; off; off >>= 1) mx = fmaxf(mx, __shfl_xor(mx, off));
        float sum = 0.f;
        for (int m = lane; m < 1024; m += 64) {
            float e = expf(p[h][m] - mx);
            p[h][m] = e;
            sum += e;
        }
        #pragma unroll
        for (int off = 32; off; off >>= 1) sum += __shfl_xor(sum, off);
        float rinv = 1.0f / sum;
        for (int m = lane; m < 1024; m += 64) p[h][m] *= rinv;
    }
    __syncthreads();

    for (int m = tid; m < 1024; m += 256) {
        float ph[8];
        #pragma unroll
        for (int h = 0; h < 8; ++h) ph[h] = p[h][m];
        #pragma unroll
        for (int o = 0; o < 8; ++o) {
            float accv = s_bias2[o];
            #pragma unroll
            for (int h = 0; h < 8; ++h) accv += s_w2[o][h] * ph[h];
            attn[((size_t)(b * 8 + o) * 1024 + n) * 1024 + m] = accv;
        }
    }
}

// ---------------------------------------------------------------------------
// Kernel 4: out1[b,n,h*96+d] = sum_m attn[b,h,n,m] * v[b,h,m,d]
// 128(n) x 96(d) tile per block, 8x6 per thread, K chunk 32.
// ---------------------------------------------------------------------------
__global__ __launch_bounds__(256) void pv_gemm(
    const float* __restrict__ attn, const float* __restrict__ v,
    float* __restrict__ out1)
{
    const int bh = blockIdx.y;
    const int b = bh >> 3, h = bh & 7;
    const float* ap = attn + (size_t)bh * N_ * N_;
    const float* vp = v + (size_t)bh * N_ * D_;
    const int n0 = blockIdx.x * 128;

    __shared__ __align__(16) float As[32][132];  // [m][n]
    __shared__ __align__(16) float Bs[32][100];  // [m][d]

    float acc[8][6];
    #pragma unroll
    for (int i = 0; i < 8; ++i)
        #pragma unroll
        for (int j = 0; j < 6; ++j) acc[i][j] = 0.f;

    const int tid = threadIdx.x, tx = tid & 15, ty = tid >> 4;

    for (int mc = 0; mc < 1024; mc += 32) {
        #pragma unroll
        for (int it = 0; it < 16; ++it) {
            int e = tid + it * 256;
            int i = e >> 5, kk = e & 31;
            As[kk][i] = ap[(size_t)(n0 + i) * 1024 + mc + kk];
        }
        for (int e = tid; e < 3072; e += 256) {
            int kk = e / 96, d = e % 96;
            Bs[kk][d] = vp[(size_t)(mc + kk) * 96 + d];
        }
        __syncthreads();
        #pragma unroll
        for (int kk = 0; kk < 32; ++kk) {
            float4 a0 = *(const float4*)&As[kk][ty * 8];
            float4 a1 = *(const float4*)&As[kk][ty * 8 + 4];
            float av[8] = {a0.x, a0.y, a0.z, a0.w, a1.x, a1.y, a1.z, a1.w};
            float bv[6];
            #pragma unroll
            for (int j = 0; j < 6; ++j) bv[j] = Bs[kk][tx * 6 + j];
            #pragma unroll
            for (int i = 0; i < 8; ++i)
                #pragma unroll
                for (int j = 0; j < 6; ++j)
                    acc[i][j] += av[i] * bv[j];
        }
        __syncthreads();
    }

    #pragma unroll
    for (int i = 0; i < 8; ++i)
        #pragma unroll
        for (int j = 0; j < 6; ++j)
            out1[((size_t)b * 1024 + (n0 + ty * 8 + i)) * 768 + h * 96 + tx * 6 + j] = acc[i][j];
}

// ---------------------------------------------------------------------------
// Kernel 5: out[t][o] = sum_c out1[t][c] * pw[o][c] + pb[o]
// (8192 x 768) = (8192 x 768) @ (768 x 768)^T ; 128x128 tile, 8x8 per thread.
// ---------------------------------------------------------------------------
__global__ __launch_bounds__(256) void proj_gemm(
    const float* __restrict__ out1, const float* __restrict__ pw,
    const float* __restrict__ pb, float* __restrict__ out)
{
    const int t0 = blockIdx.y * 128, o0 = blockIdx.x * 128;

    __shared__ __align__(16) float As[32][132];  // [kk][t]
    __shared__ __align__(16) float Bs[32][132];  // [kk][o]

    float acc[8][8];
    #pragma unroll
    for (int i = 0; i < 8; ++i)
        #pragma unroll
        for (int j = 0; j < 8; ++j) acc[i][j] = 0.f;

    const int tid = threadIdx.x, tx = tid & 15, ty = tid >> 4;

    for (int kc = 0; kc < 768; kc += 32) {
        #pragma unroll
        for (int it = 0; it < 16; ++it) {
            int e = tid + it * 256;
            int i = e >> 5, kk = e & 31;
            As[kk][i] = out1[(size_t)(t0 + i) * 768 + kc + kk];
            Bs[kk][i] = pw[(size_t)(o0 + i) * 768 + kc + kk];
        }
        __syncthreads();
        #pragma unroll
        for (int kk = 0; kk < 32; ++kk) {
            float4 a0 = *(const float4*)&As[kk][ty * 8];
            float4 a1 = *(const float4*)&As[kk][ty * 8 + 4];
            float4 b0 = *(const float4*)&Bs[kk][tx * 8];
            float4 b1 = *(const float4*)&Bs[kk][tx * 8 + 4];
            float av[8] = {a0.x, a0.y, a0.z, a0.w, a1.x, a1.y, a1.z, a1.w};
            float bv[8] = {b0.x, b0.y, b0.z, b0.w, b1.x, b1.y, b1.z, b1.w};
            #pragma unroll
            for (int i = 0; i < 8; ++i)
                #pragma unroll
                for (int j = 0; j < 8; ++j)
                    acc[i][j] += av[i] * bv[j];
        }
        __syncthreads();
    }

    float4 pb0 = *(const float4*)&pb[o0 + tx * 8];
    float4 pb1 = *(const float4*)&pb[o0 + tx * 8 + 4];
    #pragma unroll
    for (int i = 0; i < 8; ++i) {
        size_t row = (size_t)(t0 + ty * 8 + i) * 768 + o0 + tx * 8;
        float4 s0 = make_float4(acc[i][0] + pb0.x, acc[i][1] + pb0.y,
                                acc[i][2] + pb0.z, acc[i][3] + pb0.w);
        float4 s1 = make_float4(acc[i][4] + pb1.x, acc[i][5] + pb1.y,
                                acc[i][6] + pb1.z, acc[i][7] + pb1.w);
        *(float4*)&out[row] = s0;
        *(float4*)&out[row + 4] = s1;
    }
}

// ---------------------------------------------------------------------------
extern "C" void kernel_launch(void* const* d_in, const int* in_sizes, int n_in,
                              void* d_out, int out_size, void* d_ws, size_t ws_size,
                              hipStream_t stream)
{
    const float* x    = (const float*)d_in[0];
    const float* qw   = (const float*)d_in[1];
    const float* qb   = (const float*)d_in[2];
    const float* kw   = (const float*)d_in[3];
    const float* kb   = (const float*)d_in[4];
    const float* vw   = (const float*)d_in[5];
    const float* vb   = (const float*)d_in[6];
    const float* rw   = (const float*)d_in[7];
    const float* rb   = (const float*)d_in[8];
    const float* bn_g = (const float*)d_in[9];
    const float* bn_b = (const float*)d_in[10];
    const float* bn_m = (const float*)d_in[11];
    const float* bn_v = (const float*)d_in[12];
    const float* pw   = (const float*)d_in[13];
    const float* pb   = (const float*)d_in[14];

    float* out_p  = (float*)d_out;                       // (B, N, C)
    float* attn_p = out_p + (size_t)B_ * N_ * C_;        // (B, H, N, N)

    float* ws   = (float*)d_ws;
    const size_t qkv_sz = (size_t)B_ * H_ * N_ * D_;     // 6,291,456
    float* qbuf = ws;
    float* kbuf = ws + qkv_sz;
    float* vbuf = ws + 2 * qkv_sz;
    float* out1 = ws;  // reuse q region (dead after qk_gemm)

    conv_qkv<<<B_ * N_, 256, 0, stream>>>(x, qw, qb, kw, kb, vw, vb, qbuf, kbuf, vbuf);
    qk_gemm<<<dim3(8, 8, 64), 256, 0, stream>>>(qbuf, kbuf, attn_p);
    softmax_mix<<<B_ * N_, 256, 0, stream>>>(attn_p, rw, rb, bn_g, bn_b, bn_m, bn_v);
    pv_gemm<<<dim3(8, 64), 256, 0, stream>>>(attn_p, vbuf, out1);
    proj_gemm<<<dim3(6, 64), 256, 0, stream>>>(out1, pw, pb, out_p);
}

// Round 2
// 426.203 us; speedup vs baseline: 2.8440x; 2.8440x over previous
//
#include <hip/hip_runtime.h>
#include <math.h>

#define B_ 8
#define N_ 1024
#define C_ 768
#define H_ 8
#define D_ 96
#define SCALE_F 0.1020620726159657f /* 96^-0.5 */

typedef unsigned short u16;
typedef __bf16 bf16x8 __attribute__((ext_vector_type(8)));
typedef float f32x4 __attribute__((ext_vector_type(4)));

#define MFMA(a, b, c) __builtin_amdgcn_mfma_f32_16x16x32_bf16(a, b, c, 0, 0, 0)

__device__ inline void split1(float x, u16& h, u16& l) {
    __bf16 hb = (__bf16)x;                  // RNE
    float hf = (float)hb;
    __bf16 lb = (__bf16)(x - hf);           // residual, RNE
    h = __builtin_bit_cast(u16, hb);
    l = __builtin_bit_cast(u16, lb);
}

__device__ inline void split4(float4 x, ushort4& h, ushort4& l) {
    split1(x.x, h.x, l.x);
    split1(x.y, h.y, l.y);
    split1(x.z, h.z, l.z);
    split1(x.w, h.w, l.w);
}

// ---------------------------------------------------------------------------
// Kernel 1: conv3x3 (SAME) on 8192 images of 3x16x16 -> q, k, v f32 (B,H,N,D)
// ---------------------------------------------------------------------------
__global__ __launch_bounds__(256) void conv_qkv(
    const float* __restrict__ x,
    const float* __restrict__ qw, const float* __restrict__ qb,
    const float* __restrict__ kw, const float* __restrict__ kb,
    const float* __restrict__ vw, const float* __restrict__ vb,
    float* __restrict__ q, float* __restrict__ k, float* __restrict__ v)
{
    __shared__ float simg[768];
    __shared__ float sw[243];
    __shared__ float sb[9];
    const int img = blockIdx.x;
    const int b = img >> 10;
    const int tid = threadIdx.x;

    for (int i = tid; i < 768; i += 256) simg[i] = x[(size_t)img * 768 + i];
    if (tid < 243) {
        int g = tid / 81, i = tid % 81;
        const float* w = (g == 0) ? qw : (g == 1) ? kw : vw;
        sw[tid] = w[i];
    }
    if (tid < 9) {
        int g = tid / 3, i = tid % 3;
        const float* bb = (g == 0) ? qb : (g == 1) ? kb : vb;
        sb[tid] = bb[i];
    }
    __syncthreads();

    const int n = img & 1023;
    for (int e = tid; e < 2304; e += 256) {
        int g = e / 768, c = e % 768;
        int oc = c >> 8, rem = c & 255, y = rem >> 4, xx = rem & 15;
        float acc = sb[g * 3 + oc];
        const float* wg = &sw[g * 81 + oc * 27];
        #pragma unroll
        for (int ic = 0; ic < 3; ++ic)
            #pragma unroll
            for (int ky = 0; ky < 3; ++ky) {
                int yy = y + ky - 1;
                if (yy < 0 || yy > 15) continue;
                #pragma unroll
                for (int kx = 0; kx < 3; ++kx) {
                    int xp = xx + kx - 1;
                    if (xp < 0 || xp > 15) continue;
                    acc += wg[ic * 9 + ky * 3 + kx] * simg[ic * 256 + yy * 16 + xp];
                }
            }
        int h = c / 96, d = c % 96;
        float* dst = (g == 0) ? q : (g == 1) ? k : v;
        dst[((size_t)(b * 8 + h) * 1024 + n) * 96 + d] = acc;
    }
}

// ---------------------------------------------------------------------------
// Kernel 2: QK^T via MFMA bf16 split. logits[n][m] = SCALE * q.k
// Block: 128x128 tile, 4 waves (2x2), each wave 64x64 = 4x4 fragments.
// ---------------------------------------------------------------------------
__global__ __launch_bounds__(256) void qk_mfma(
    const float* __restrict__ q, const float* __restrict__ k,
    float* __restrict__ logits)
{
    __shared__ __align__(16) u16 Qh[5120], Ql[5120], Kh[5120], Kl[5120]; // [128][40]
    const int bh = blockIdx.z;
    const float* qp = q + (size_t)bh * N_ * D_;
    const float* kp = k + (size_t)bh * N_ * D_;
    float* lp = logits + (size_t)bh * N_ * N_;
    const int n0 = blockIdx.y * 128, m0 = blockIdx.x * 128;
    const int tid = threadIdx.x;
    const int wid = tid >> 6, lane = tid & 63;
    const int l16 = lane & 15, kg = lane >> 4;
    const int wr = wid >> 1, wc = wid & 1;

    f32x4 acc[4][4];
    #pragma unroll
    for (int i = 0; i < 4; ++i)
        #pragma unroll
        for (int j = 0; j < 4; ++j) acc[i][j] = (f32x4){0.f, 0.f, 0.f, 0.f};

    for (int s = 0; s < 3; ++s) {
        const int kc = s * 32;
        if (s) __syncthreads();
        #pragma unroll
        for (int i = 0; i < 4; ++i) {
            int idx = tid + i * 256;
            int r = idx >> 3, c4 = idx & 7;
            float4 xq = *(const float4*)&qp[(size_t)(n0 + r) * 96 + kc + c4 * 4];
            float4 xk = *(const float4*)&kp[(size_t)(m0 + r) * 96 + kc + c4 * 4];
            ushort4 h, l;
            split4(xq, h, l);
            *(ushort4*)&Qh[r * 40 + c4 * 4] = h;
            *(ushort4*)&Ql[r * 40 + c4 * 4] = l;
            split4(xk, h, l);
            *(ushort4*)&Kh[r * 40 + c4 * 4] = h;
            *(ushort4*)&Kl[r * 40 + c4 * 4] = l;
        }
        __syncthreads();

        bf16x8 ah[4], al[4], bh8[4], bl8[4];
        #pragma unroll
        for (int f = 0; f < 4; ++f) {
            int ra = (wr * 64 + f * 16 + l16) * 40 + kg * 8;
            ah[f] = *(const bf16x8*)&Qh[ra];
            al[f] = *(const bf16x8*)&Ql[ra];
            int rb = (wc * 64 + f * 16 + l16) * 40 + kg * 8;
            bh8[f] = *(const bf16x8*)&Kh[rb];
            bl8[f] = *(const bf16x8*)&Kl[rb];
        }
        #pragma unroll
        for (int i = 0; i < 4; ++i)
            #pragma unroll
            for (int j = 0; j < 4; ++j) {
                acc[i][j] = MFMA(ah[i], bh8[j], acc[i][j]);
                acc[i][j] = MFMA(ah[i], bl8[j], acc[i][j]);
                acc[i][j] = MFMA(al[i], bh8[j], acc[i][j]);
            }
    }

    #pragma unroll
    for (int i = 0; i < 4; ++i) {
        int rr = n0 + wr * 64 + i * 16 + kg * 4;
        #pragma unroll
        for (int j = 0; j < 4; ++j) {
            int cc = m0 + wc * 64 + j * 16 + l16;
            #pragma unroll
            for (int r = 0; r < 4; ++r)
                lp[(size_t)(rr + r) * 1024 + cc] = acc[i][j][r] * SCALE_F;
        }
    }
}

// ---------------------------------------------------------------------------
// Kernel 3: softmax over m for each (b,h,n), then head-mix + BN, in place.
// float4 vectorized; 1/sum folded into mix weights (no 3rd pass).
// ---------------------------------------------------------------------------
__global__ __launch_bounds__(256) void softmax_mix(
    float* __restrict__ attn,
    const float* __restrict__ rw, const float* __restrict__ rb,
    const float* __restrict__ bn_g, const float* __restrict__ bn_b,
    const float* __restrict__ bn_m, const float* __restrict__ bn_v)
{
    __shared__ float p[8][1024];
    __shared__ float s_w2[8][8];
    __shared__ float s_bias2[8];
    __shared__ float s_rinv[8];

    const int bn_idx = blockIdx.x;
    const int b = bn_idx >> 10, n = bn_idx & 1023;
    const int tid = threadIdx.x;

    if (tid < 64) {
        int o = tid >> 3, h = tid & 7;
        float inv = bn_g[o] * rsqrtf(bn_v[o] + 1e-5f);
        s_w2[o][h] = rw[o * 8 + h] * inv;
        if (h == 0) s_bias2[o] = (rb[o] - bn_m[o]) * inv + bn_b[o];
    }

    #pragma unroll
    for (int h = 0; h < 8; ++h) {
        float4 x = *(const float4*)&attn[((size_t)(b * 8 + h) * 1024 + n) * 1024 + tid * 4];
        *(float4*)&p[h][tid * 4] = x;
    }
    __syncthreads();

    const int wave = tid >> 6, lane = tid & 63;
    #pragma unroll
    for (int r = 0; r < 2; ++r) {
        int h = wave * 2 + r;
        float4 v[4];
        float mx = -INFINITY;
        #pragma unroll
        for (int i = 0; i < 4; ++i) {
            v[i] = *(const float4*)&p[h][(lane + 64 * i) * 4];
            mx = fmaxf(mx, fmaxf(fmaxf(v[i].x, v[i].y), fmaxf(v[i].z, v[i].w)));
        }
        #pragma unroll
        for (int off = 32; off; off >>= 1) mx = fmaxf(mx, __shfl_xor(mx, off));
        float sum = 0.f;
        #pragma unroll
        for (int i = 0; i < 4; ++i) {
            float4 e;
            e.x = expf(v[i].x - mx); e.y = expf(v[i].y - mx);
            e.z = expf(v[i].z - mx); e.w = expf(v[i].w - mx);
            sum += (e.x + e.y) + (e.z + e.w);
            *(float4*)&p[h][(lane + 64 * i) * 4] = e;
        }
        #pragma unroll
        for (int off = 32; off; off >>= 1) sum += __shfl_xor(sum, off);
        if (lane == 0) s_rinv[h] = 1.0f / sum;
    }
    __syncthreads();

    {
        float4 ph[8];
        #pragma unroll
        for (int h = 0; h < 8; ++h) ph[h] = *(const float4*)&p[h][tid * 4];
        #pragma unroll
        for (int o = 0; o < 8; ++o) {
            float bz = s_bias2[o];
            float4 r4 = make_float4(bz, bz, bz, bz);
            #pragma unroll
            for (int h = 0; h < 8; ++h) {
                float w = s_w2[o][h] * s_rinv[h];
                r4.x += w * ph[h].x; r4.y += w * ph[h].y;
                r4.z += w * ph[h].z; r4.w += w * ph[h].w;
            }
            *(float4*)&attn[((size_t)(b * 8 + o) * 1024 + n) * 1024 + tid * 4] = r4;
        }
    }
}

// ---------------------------------------------------------------------------
// Kernel 4: transpose+split V: (b,h,n,d) f32 -> vt_h/vt_l (b,h,d,n) bf16
// ---------------------------------------------------------------------------
__global__ __launch_bounds__(256) void vt_split(
    const float* __restrict__ v, u16* __restrict__ vt_h, u16* __restrict__ vt_l)
{
    __shared__ float t32[32][36];
    const int bh = blockIdx.z, n0 = blockIdx.x * 32, d0 = blockIdx.y * 32;
    const int tid = threadIdx.x;
    {
        int nn = tid >> 3, c4 = (tid & 7) * 4;
        float4 x = *(const float4*)&v[((size_t)bh * 1024 + n0 + nn) * 96 + d0 + c4];
        t32[nn][c4] = x.x; t32[nn][c4 + 1] = x.y;
        t32[nn][c4 + 2] = x.z; t32[nn][c4 + 3] = x.w;
    }
    __syncthreads();
    {
        int d = tid >> 3, n4 = (tid & 7) * 4;
        float4 y = make_float4(t32[n4][d], t32[n4 + 1][d], t32[n4 + 2][d], t32[n4 + 3][d]);
        ushort4 h, l;
        split4(y, h, l);
        size_t o = ((size_t)bh * 96 + d0 + d) * 1024 + n0 + n4;
        *(ushort4*)&vt_h[o] = h;
        *(ushort4*)&vt_l[o] = l;
    }
}

// ---------------------------------------------------------------------------
// Kernel 5: split pw f32 -> pw_h/pw_l bf16
// ---------------------------------------------------------------------------
__global__ __launch_bounds__(256) void pw_split(
    const float* __restrict__ pw, u16* __restrict__ pwh, u16* __restrict__ pwl)
{
    int i = blockIdx.x * 256 + threadIdx.x; // float4 index, 147456 total
    float4 x = *(const float4*)&pw[(size_t)i * 4];
    ushort4 h, l;
    split4(x, h, l);
    *(ushort4*)&pwh[(size_t)i * 4] = h;
    *(ushort4*)&pwl[(size_t)i * 4] = l;
}

// ---------------------------------------------------------------------------
// Kernel 6: PV via MFMA. out1[n][h*96+d] = sum_m attn[n][m] * v[m][d]
// Block: 128n x 96d, 4 waves (32 rows each), k double-buffered in regs.
// ---------------------------------------------------------------------------
#define PV_LOAD(S, A, BH, BL)                                                   \
    {                                                                           \
        int mc_ = (S) * 32;                                                     \
        _Pragma("unroll")                                                       \
        for (int i_ = 0; i_ < 4; ++i_) {                                        \
            int idx_ = tid + i_ * 256, r_ = idx_ >> 3, c4_ = idx_ & 7;          \
            A[i_] = *(const float4*)&ap[(size_t)(n0 + r_) * 1024 + mc_ + c4_ * 4]; \
        }                                                                       \
        _Pragma("unroll")                                                       \
        for (int i_ = 0; i_ < 3; ++i_) {                                        \
            int idx_ = tid + i_ * 256, d_ = idx_ >> 3, mq_ = idx_ & 7;          \
            BH[i_] = *(const ushort4*)&vhp[(size_t)d_ * 1024 + mc_ + mq_ * 4];  \
            BL[i_] = *(const ushort4*)&vlp[(size_t)d_ * 1024 + mc_ + mq_ * 4];  \
        }                                                                       \
    }

#define PV_STAGE(A, BH, BL)                                                     \
    {                                                                           \
        _Pragma("unroll")                                                       \
        for (int i_ = 0; i_ < 4; ++i_) {                                        \
            int idx_ = tid + i_ * 256, r_ = idx_ >> 3, c4_ = idx_ & 7;          \
            ushort4 h_, l_;                                                     \
            split4(A[i_], h_, l_);                                              \
            *(ushort4*)&Ah[r_ * 40 + c4_ * 4] = h_;                             \
            *(ushort4*)&Al[r_ * 40 + c4_ * 4] = l_;                             \
        }                                                                       \
        _Pragma("unroll")                                                       \
        for (int i_ = 0; i_ < 3; ++i_) {                                        \
            int idx_ = tid + i_ * 256, d_ = idx_ >> 3, mq_ = idx_ & 7;          \
            *(ushort4*)&Bh[d_ * 40 + mq_ * 4] = BH[i_];                         \
            *(ushort4*)&Bl[d_ * 40 + mq_ * 4] = BL[i_];                         \
        }                                                                       \
    }

#define PV_COMPUTE                                                              \
    {                                                                           \
        bf16x8 ah_[2], al_[2], bh_[6], bl_[6];                                  \
        _Pragma("unroll")                                                       \
        for (int f_ = 0; f_ < 2; ++f_) {                                        \
            int ra_ = (wid * 32 + f_ * 16 + l16) * 40 + kg * 8;                 \
            ah_[f_] = *(const bf16x8*)&Ah[ra_];                                 \
            al_[f_] = *(const bf16x8*)&Al[ra_];                                 \
        }                                                                       \
        _Pragma("unroll")                                                       \
        for (int j_ = 0; j_ < 6; ++j_) {                                        \
            int rb_ = (j_ * 16 + l16) * 40 + kg * 8;                            \
            bh_[j_] = *(const bf16x8*)&Bh[rb_];                                 \
            bl_[j_] = *(const bf16x8*)&Bl[rb_];                                 \
        }                                                                       \
        _Pragma("unroll")                                                       \
        for (int i_ = 0; i_ < 2; ++i_)                                          \
            _Pragma("unroll")                                                   \
            for (int j_ = 0; j_ < 6; ++j_) {                                    \
                acc[i_][j_] = MFMA(ah_[i_], bh_[j_], acc[i_][j_]);              \
                acc[i_][j_] = MFMA(ah_[i_], bl_[j_], acc[i_][j_]);              \
                acc[i_][j_] = MFMA(al_[i_], bh_[j_], acc[i_][j_]);              \
            }                                                                   \
    }

__global__ __launch_bounds__(256) void pv_mfma(
    const float* __restrict__ attn,
    const u16* __restrict__ vt_h, const u16* __restrict__ vt_l,
    u16* __restrict__ o1h, u16* __restrict__ o1l)
{
    __shared__ __align__(16) u16 Ah[5120], Al[5120];   // [128][40]
    __shared__ __align__(16) u16 Bh[3840], Bl[3840];   // [96][40]
    const int bh = blockIdx.y;
    const int bI = bh >> 3, hI = bh & 7;
    const float* ap = attn + (size_t)bh * N_ * N_;
    const u16* vhp = vt_h + (size_t)bh * 96 * 1024;
    const u16* vlp = vt_l + (size_t)bh * 96 * 1024;
    const int n0 = blockIdx.x * 128;
    const int tid = threadIdx.x, wid = tid >> 6, lane = tid & 63;
    const int l16 = lane & 15, kg = lane >> 4;

    f32x4 acc[2][6];
    #pragma unroll
    for (int i = 0; i < 2; ++i)
        #pragma unroll
        for (int j = 0; j < 6; ++j) acc[i][j] = (f32x4){0.f, 0.f, 0.f, 0.f};

    float4 rA[4], rA2[4];
    ushort4 rBh[3], rBl[3], rBh2[3], rBl2[3];

    PV_LOAD(0, rA, rBh, rBl)
    for (int it = 0; it < 16; ++it) {
        PV_STAGE(rA, rBh, rBl)
        PV_LOAD(2 * it + 1, rA2, rBh2, rBl2)
        __syncthreads();
        PV_COMPUTE
        __syncthreads();
        PV_STAGE(rA2, rBh2, rBl2)
        if (it < 15) PV_LOAD(2 * it + 2, rA, rBh, rBl)
        __syncthreads();
        PV_COMPUTE
        __syncthreads();
    }

    #pragma unroll
    for (int i = 0; i < 2; ++i) {
        int rr = n0 + wid * 32 + i * 16 + kg * 4;
        #pragma unroll
        for (int j = 0; j < 6; ++j) {
            int cc = hI * 96 + j * 16 + l16;
            #pragma unroll
            for (int r = 0; r < 4; ++r) {
                u16 h, l;
                split1(acc[i][j][r], h, l);
                size_t o = (size_t)(bI * 1024 + rr + r) * 768 + cc;
                o1h[o] = h;
                o1l[o] = l;
            }
        }
    }
}

// ---------------------------------------------------------------------------
// Kernel 7: proj via MFMA. out[t][o] = out1[t][:] . pw[o][:] + pb[o]
// ---------------------------------------------------------------------------
__global__ __launch_bounds__(256) void proj_mfma(
    const u16* __restrict__ o1h, const u16* __restrict__ o1l,
    const u16* __restrict__ pwh, const u16* __restrict__ pwl,
    const float* __restrict__ pb, float* __restrict__ out)
{
    __shared__ __align__(16) u16 Ahs[5120], Als[5120], Bhs[5120], Bls[5120];
    const int t0 = blockIdx.y * 128, o0 = blockIdx.x * 128;
    const int tid = threadIdx.x;
    const int wid = tid >> 6, lane = tid & 63;
    const int l16 = lane & 15, kg = lane >> 4;
    const int wr = wid >> 1, wc = wid & 1;

    f32x4 acc[4][4];
    #pragma unroll
    for (int i = 0; i < 4; ++i)
        #pragma unroll
        for (int j = 0; j < 4; ++j) acc[i][j] = (f32x4){0.f, 0.f, 0.f, 0.f};

    for (int s = 0; s < 24; ++s) {
        const int kc = s * 32;
        if (s) __syncthreads();
        #pragma unroll
        for (int i = 0; i < 4; ++i) {
            int idx = tid + i * 256;
            int r = idx >> 3, c4 = idx & 7;
            *(ushort4*)&Ahs[r * 40 + c4 * 4] = *(const ushort4*)&o1h[(size_t)(t0 + r) * 768 + kc + c4 * 4];
            *(ushort4*)&Als[r * 40 + c4 * 4] = *(const ushort4*)&o1l[(size_t)(t0 + r) * 768 + kc + c4 * 4];
            *(ushort4*)&Bhs[r * 40 + c4 * 4] = *(const ushort4*)&pwh[(size_t)(o0 + r) * 768 + kc + c4 * 4];
            *(ushort4*)&Bls[r * 40 + c4 * 4] = *(const ushort4*)&pwl[(size_t)(o0 + r) * 768 + kc + c4 * 4];
        }
        __syncthreads();

        bf16x8 ah[4], al[4], bh8[4], bl8[4];
        #pragma unroll
        for (int f = 0; f < 4; ++f) {
            int ra = (wr * 64 + f * 16 + l16) * 40 + kg * 8;
            ah[f] = *(const bf16x8*)&Ahs[ra];
            al[f] = *(const bf16x8*)&Als[ra];
            int rb = (wc * 64 + f * 16 + l16) * 40 + kg * 8;
            bh8[f] = *(const bf16x8*)&Bhs[rb];
            bl8[f] = *(const bf16x8*)&Bls[rb];
        }
        #pragma unroll
        for (int i = 0; i < 4; ++i)
            #pragma unroll
            for (int j = 0; j < 4; ++j) {
                acc[i][j] = MFMA(ah[i], bh8[j], acc[i][j]);
                acc[i][j] = MFMA(ah[i], bl8[j], acc[i][j]);
                acc[i][j] = MFMA(al[i], bh8[j], acc[i][j]);
            }
    }

    #pragma unroll
    for (int i = 0; i < 4; ++i) {
        int rr = t0 + wr * 64 + i * 16 + kg * 4;
        #pragma unroll
        for (int j = 0; j < 4; ++j) {
            int cc = o0 + wc * 64 + j * 16 + l16;
            float bias = pb[cc];
            #pragma unroll
            for (int r = 0; r < 4; ++r)
                out[(size_t)(rr + r) * 768 + cc] = acc[i][j][r] + bias;
        }
    }
}

// ---------------------------------------------------------------------------
extern "C" void kernel_launch(void* const* d_in, const int* in_sizes, int n_in,
                              void* d_out, int out_size, void* d_ws, size_t ws_size,
                              hipStream_t stream)
{
    const float* x    = (const float*)d_in[0];
    const float* qw   = (const float*)d_in[1];
    const float* qb   = (const float*)d_in[2];
    const float* kw   = (const float*)d_in[3];
    const float* kb   = (const float*)d_in[4];
    const float* vw   = (const float*)d_in[5];
    const float* vb   = (const float*)d_in[6];
    const float* rw   = (const float*)d_in[7];
    const float* rb   = (const float*)d_in[8];
    const float* bn_g = (const float*)d_in[9];
    const float* bn_b = (const float*)d_in[10];
    const float* bn_m = (const float*)d_in[11];
    const float* bn_v = (const float*)d_in[12];
    const float* pw   = (const float*)d_in[13];
    const float* pb   = (const float*)d_in[14];

    float* out_p  = (float*)d_out;                  // (B, N, C)
    float* attn_p = out_p + (size_t)B_ * N_ * C_;   // (B, H, N, N)

    float* ws = (float*)d_ws;
    const size_t qkv_sz = (size_t)B_ * H_ * N_ * D_;  // 6,291,456
    float* qbuf = ws;                 // f32 q; later vt_h/vt_l (bf16)
    float* kbuf = ws + qkv_sz;        // f32 k; later o1h/o1l (bf16)
    float* vbuf = ws + 2 * qkv_sz;    // f32 v; later pw_h/pw_l (bf16)

    u16* vt_h = (u16*)qbuf;
    u16* vt_l = vt_h + qkv_sz;
    u16* o1h  = (u16*)kbuf;
    u16* o1l  = o1h + qkv_sz;
    u16* pwh  = (u16*)vbuf;
    u16* pwl  = pwh + (size_t)C_ * C_;

    conv_qkv<<<B_ * N_, 256, 0, stream>>>(x, qw, qb, kw, kb, vw, vb, qbuf, kbuf, vbuf);
    qk_mfma<<<dim3(8, 8, 64), 256, 0, stream>>>(qbuf, kbuf, attn_p);
    softmax_mix<<<B_ * N_, 256, 0, stream>>>(attn_p, rw, rb, bn_g, bn_b, bn_m, bn_v);
    vt_split<<<dim3(32, 3, 64), 256, 0, stream>>>(vbuf, vt_h, vt_l);   // q dead -> vt in qbuf
    pw_split<<<576, 256, 0, stream>>>(pw, pwh, pwl);                   // v dead -> pw in vbuf
    pv_mfma<<<dim3(8, 64), 256, 0, stream>>>(attn_p, vt_h, vt_l, o1h, o1l); // k dead -> o1 in kbuf
    proj_mfma<<<dim3(6, 64), 256, 0, stream>>>(o1h, o1l, pwh, pwl, pb, out_p);
}